// Round 10
// baseline (875.891 us; speedup 1.0000x reference)
//
#include <hip/hip_runtime.h>
#include <math.h>

#define BFULL 8
#define HH 64
#define WWI 64
#define CC 256
#define NN 16384
#define INDIM 810
#define XP 832          // X padded cols (zero-filled 810..831)
#define K3P 1088        // concat layer K padded (256 + 832)
#define MLPW 256

typedef unsigned short u16;
typedef __attribute__((ext_vector_type(8))) short short8;
typedef __attribute__((ext_vector_type(4))) float f32x4;

__device__ __forceinline__ u16 f2bf(float f){
  union{float f; unsigned u;} v; v.f=f;
  unsigned r = v.u + 0x7FFFu + ((v.u>>16)&1u);   // RNE
  return (u16)(r>>16);
}
__device__ __forceinline__ float bf2f(u16 h){
  union{unsigned u; float f;} v; v.u = ((unsigned)h)<<16; return v.f;
}
__device__ __forceinline__ float gelu_tanh(float x){
  float x3 = x*x*x;
  float t = tanhf(0.7978845608028654f*(x + 0.044715f*x3));
  return 0.5f*x*(1.0f+t);
}

// ---------------- pyramid resize (jax.image.resize bilinear, antialias=True) ----------------
template<int OUTD, int RR>
__global__ __launch_bounds__(256) void resize_kernel(const float* __restrict__ in,
                                                     float* __restrict__ out){
  int bidx = blockIdx.x;
  int ox = bidx % OUTD;
  int oy = (bidx / OUTD) % OUTD;
  int b  = bidx / (OUTD*OUTD);
  int c = threadIdx.x;

  float sy = (oy + 0.5f)*RR - 0.5f;
  float sx = (ox + 0.5f)*RR - 0.5f;
  int jy0 = (int)floorf(sy) - RR + 1;
  int jx0 = (int)floorf(sx) - RR + 1;

  float wy[2*RR], wx[2*RR];
  int   jys[2*RR], jxs[2*RR];
  int cy=0, cx=0; float sumy=0.f, sumx=0.f;
  #pragma unroll
  for(int t=0;t<2*RR;t++){
    int j = jy0 + t;
    if(j>=0 && j<HH){
      float w = 1.0f - fabsf((float)j - sy)/(float)RR;
      if(w > 0.f){ jys[cy]=j; wy[cy]=w; sumy+=w; cy++; }
    }
  }
  #pragma unroll
  for(int t=0;t<2*RR;t++){
    int j = jx0 + t;
    if(j>=0 && j<WWI){
      float w = 1.0f - fabsf((float)j - sx)/(float)RR;
      if(w > 0.f){ jxs[cx]=j; wx[cx]=w; sumx+=w; cx++; }
    }
  }
  float acc = 0.f;
  for(int i=0;i<cy;i++)
    for(int j=0;j<cx;j++)
      acc += wy[i]*wx[j]*in[(((size_t)b*HH + jys[i])*WWI + jxs[j])*CC + c];
  acc /= (sumy*sumx);
  out[(((size_t)b*OUTD + oy)*OUTD + ox)*CC + c] = acc;
}

// ---------------- posenc + pyramid sampling -> X rows [chunk][XP] (bf16) ----------------
__global__ __launch_bounds__(256) void sample_encode(
    const float* __restrict__ fg, const float* __restrict__ pyr1,
    const float* __restrict__ pyr2, const float* __restrict__ coords,
    u16* __restrict__ X, int m0, int mcount){
  int mi = blockIdx.x;
  if(mi >= mcount) return;
  int m = m0 + mi;
  int b = m / NN;
  int n = m % NN;
  float c0 = coords[(size_t)n*2 + 0];
  float c1 = coords[(size_t)n*2 + 1];
  u16* xrow = X + (size_t)mi*XP;
  int t = threadIdx.x;

  if(t < 42){
    float v;
    if(t < 2){ v = (t==0) ? c0 : c1; }
    else {
      int k = (t-2) >> 2;
      int r = (t-2) & 3;
      float f = (float)(1u<<k) * 3.14159265358979323846f;
      float a = (r & 1) ? c1 : c0;
      v = (r < 2) ? sinf(a*f) : cosf(a*f);
    }
    xrow[t] = f2bf(v);
  }
  if(t < XP - INDIM) xrow[INDIM + t] = 0;   // zero padding cols 810..831

  const float* grids[3];
  grids[0] = fg   + (size_t)b*HH*WWI*CC;
  grids[1] = pyr1 + (size_t)b*32*32*CC;
  grids[2] = pyr2 + (size_t)b*16*16*CC;
  const int dims[3] = {64, 32, 16};

  #pragma unroll
  for(int lvl=0; lvl<3; lvl++){
    int d = dims[lvl];
    float yy = (c0 + 1.0f)*0.5f*(float)(d-1);
    float xx = (c1 + 1.0f)*0.5f*(float)(d-1);
    yy = fminf(fmaxf(yy, 0.0f), (float)(d-1));
    xx = fminf(fmaxf(xx, 0.0f), (float)(d-1));
    int y0 = (int)yy, x0 = (int)xx;
    int y1 = min(y0+1, d-1), x1 = min(x0+1, d-1);
    float ty = yy - (float)y0, tx = xx - (float)x0;
    const float* g = grids[lvl];
    float v00 = g[((size_t)y0*d + x0)*CC + t];
    float v01 = g[((size_t)y0*d + x1)*CC + t];
    float v10 = g[((size_t)y1*d + x0)*CC + t];
    float v11 = g[((size_t)y1*d + x1)*CC + t];
    float v = (1.f-ty)*((1.f-tx)*v00 + tx*v01) + ty*((1.f-tx)*v10 + tx*v11);
    xrow[42 + lvl*CC + t] = f2bf(v);
  }
}

// ---------------- weight convert: W[k][256] fp32 -> Wb[n][Kp] bf16 (B^T, zero-padded) ------
__global__ __launch_bounds__(256) void wconv(const float* __restrict__ W,
                                             u16* __restrict__ Wb, int K, int Kp){
  int idx = blockIdx.x*256 + threadIdx.x;
  if(idx >= 256*Kp) return;
  int n = idx / Kp, k = idx % Kp;
  float v = (k < K) ? W[(size_t)k*MLPW + n] : 0.f;
  Wb[idx] = f2bf(v);
}

// ---------------- MFMA GEMM: C = gelu(concat(A1,A2) @ W + bias), bf16 in/out ----------------
// 128x128 tile, 4 waves, each wave 64x64 (4x4 frags of 16x16x32), BK=32
#define GBM 128
#define GBN 128
#define LDA 80   // padded ushorts per LDS row (160B, 16B-aligned)
__global__ __launch_bounds__(256) void gemm_mfma(
    const u16* __restrict__ A1, int lda1, int w1,
    const u16* __restrict__ A2, int lda2,
    const u16* __restrict__ Wb, int Kp,
    const float* __restrict__ bias,
    u16* __restrict__ C){
  __shared__ u16 As[GBM*LDA];
  __shared__ u16 Bs[GBN*LDA];
  int tid = threadIdx.x;
  int brow = blockIdx.x, bcol = blockIdx.y;
  int lane = tid & 63, wv = tid >> 6;
  int wr = (wv>>1)*64, wc = (wv&1)*64;

  f32x4 acc[4][4];
  #pragma unroll
  for(int i=0;i<4;i++)
    #pragma unroll
    for(int j=0;j<4;j++)
      acc[i][j] = (f32x4){0.f,0.f,0.f,0.f};

  int srow = tid & 127, shalf = tid >> 7;
  size_t arow_g = (size_t)brow*GBM + srow;
  const u16* arow1 = A1 + arow_g*(size_t)lda1;
  const u16* arow2 = A2 ? (A2 + arow_g*(size_t)lda2) : (const u16*)0;
  const u16* browp = Wb + ((size_t)bcol*GBN + srow)*(size_t)Kp;

  for(int kt=0; kt<Kp; kt+=32){
    int gk = kt + shalf*16;
    const u16* asrc = (gk < w1) ? (arow1 + gk) : (arow2 + (gk - w1));
    uint4 a0 = *(const uint4*)(asrc);
    uint4 a1 = *(const uint4*)(asrc + 8);
    uint4 b0 = *(const uint4*)(browp + gk);
    uint4 b1 = *(const uint4*)(browp + gk + 8);
    __syncthreads();                       // prior iter's LDS reads done
    *(uint4*)&As[srow*LDA + shalf*16]     = a0;
    *(uint4*)&As[srow*LDA + shalf*16 + 8] = a1;
    *(uint4*)&Bs[srow*LDA + shalf*16]     = b0;
    *(uint4*)&Bs[srow*LDA + shalf*16 + 8] = b1;
    __syncthreads();

    int rl = lane & 15;
    int koff = (lane >> 4) * 8;
    short8 af[4], bf[4];
    #pragma unroll
    for(int f=0; f<4; f++){
      af[f] = *(const short8*)&As[(wr + f*16 + rl)*LDA + koff];
      bf[f] = *(const short8*)&Bs[(wc + f*16 + rl)*LDA + koff];
    }
    #pragma unroll
    for(int i=0;i<4;i++)
      #pragma unroll
      for(int j=0;j<4;j++)
        acc[i][j] = __builtin_amdgcn_mfma_f32_16x16x32_bf16(af[i], bf[j], acc[i][j], 0,0,0);
  }

  int cl = lane & 15, rg = (lane>>4)*4;
  #pragma unroll
  for(int j=0;j<4;j++){
    int ncol = bcol*GBN + wc + j*16 + cl;
    float bv = bias[ncol];
    #pragma unroll
    for(int i=0;i<4;i++){
      #pragma unroll
      for(int r=0;r<4;r++){
        size_t mrow = (size_t)brow*GBM + wr + i*16 + rg + r;
        float v = acc[i][j][r] + bv;
        v = gelu_tanh(v);
        C[mrow*(size_t)MLPW + ncol] = f2bf(v);
      }
    }
  }
}

// ---------------- final 256 -> 3 + tanh, one wave per row ----------------
__global__ __launch_bounds__(256) void out_kernel(
    const u16* __restrict__ Hin, const float* __restrict__ wout,
    const float* __restrict__ bout, float* __restrict__ out,
    int m0, int mcount){
  int wave = threadIdx.x >> 6;
  int lane = threadIdx.x & 63;
  int mi = blockIdx.x*4 + wave;
  if(mi >= mcount) return;
  const u16* hrow = Hin + (size_t)mi*MLPW;
  float a0=0.f, a1=0.f, a2=0.f;
  #pragma unroll
  for(int i=0;i<4;i++){
    int k = lane + 64*i;
    float hv = bf2f(hrow[k]);
    a0 += hv*wout[(size_t)k*3 + 0];
    a1 += hv*wout[(size_t)k*3 + 1];
    a2 += hv*wout[(size_t)k*3 + 2];
  }
  #pragma unroll
  for(int off=32; off; off>>=1){
    a0 += __shfl_down(a0, off);
    a1 += __shfl_down(a1, off);
    a2 += __shfl_down(a2, off);
  }
  if(lane == 0){
    size_t m = (size_t)(m0 + mi);
    out[m*3+0] = tanhf(a0 + bout[0]);
    out[m*3+1] = tanhf(a1 + bout[1]);
    out[m*3+2] = tanhf(a2 + bout[2]);
  }
}

extern "C" void kernel_launch(void* const* d_in, const int* in_sizes, int n_in,
                              void* d_out, int out_size, void* d_ws, size_t ws_size,
                              hipStream_t stream){
  const float* fg     = (const float*)d_in[0];
  const float* coords = (const float*)d_in[1];
  const float* w0 = (const float*)d_in[2];  const float* b0 = (const float*)d_in[3];
  const float* w1 = (const float*)d_in[4];  const float* b1 = (const float*)d_in[5];
  const float* w2 = (const float*)d_in[6];  const float* b2 = (const float*)d_in[7];
  const float* w3 = (const float*)d_in[8];  const float* b3 = (const float*)d_in[9];
  const float* wo = (const float*)d_in[10]; const float* bo = (const float*)d_in[11];
  float* out = (float*)d_out;

  char* ws = (char*)d_ws;
  size_t off = 0;
  auto alloc = [&](size_t bytes)->void*{
    void* p = ws + off;
    off += (bytes + 255) & ~(size_t)255;
    return p;
  };
  auto rnd = [](size_t bytes)->size_t{ return (bytes + 255) & ~(size_t)255; };

  // fixed allocations (sizes known up front)
  size_t fixed =
      rnd((size_t)BFULL*32*32*CC*4) + rnd((size_t)BFULL*16*16*CC*4) +
      rnd((size_t)256*XP*2) + rnd((size_t)256*256*2) +
      rnd((size_t)256*256*2) + rnd((size_t)256*K3P*2);

  const size_t Mtot = (size_t)BFULL*NN; // 131072
  size_t chunk = Mtot;
  while(chunk > 128){
    size_t need = fixed + rnd(chunk*(size_t)XP*2) + 2*rnd(chunk*(size_t)MLPW*2);
    if(need <= ws_size) break;
    chunk >>= 1;
  }
  // hard guard: if even the minimum config can't fit, launch nothing rather
  // than corrupt memory (bench will fail with a clean absmax mismatch ->
  // diagnostic that ws_size is the problem).
  size_t min_need = fixed + rnd(chunk*(size_t)XP*2) + 2*rnd(chunk*(size_t)MLPW*2);
  if(min_need > ws_size || (chunk % 128) != 0) return;

  float* pyr1 = (float*)alloc((size_t)BFULL*32*32*CC*4);
  float* pyr2 = (float*)alloc((size_t)BFULL*16*16*CC*4);
  u16* wb0 = (u16*)alloc((size_t)256*XP*2);
  u16* wb1 = (u16*)alloc((size_t)256*256*2);
  u16* wb2 = (u16*)alloc((size_t)256*256*2);
  u16* wb3 = (u16*)alloc((size_t)256*K3P*2);
  u16* X  = (u16*)alloc(chunk*(size_t)XP*2);
  u16* Ha = (u16*)alloc(chunk*(size_t)MLPW*2);
  u16* Hb = (u16*)alloc(chunk*(size_t)MLPW*2);

  resize_kernel<32,2><<<dim3(BFULL*32*32), dim3(256), 0, stream>>>(fg, pyr1);
  resize_kernel<16,4><<<dim3(BFULL*16*16), dim3(256), 0, stream>>>(fg, pyr2);
  wconv<<<dim3((256*XP +255)/256), dim3(256), 0, stream>>>(w0, wb0, INDIM, XP);
  wconv<<<dim3((256*256 +255)/256), dim3(256), 0, stream>>>(w1, wb1, 256, 256);
  wconv<<<dim3((256*256 +255)/256), dim3(256), 0, stream>>>(w2, wb2, 256, 256);
  wconv<<<dim3((256*K3P +255)/256), dim3(256), 0, stream>>>(w3, wb3, MLPW+INDIM, K3P);

  for(size_t m0=0; m0<Mtot; m0+=chunk){
    int mc = (int)chunk;
    sample_encode<<<dim3(mc), dim3(256), 0, stream>>>(fg, pyr1, pyr2, coords, X, (int)m0, mc);
    dim3 ggrid(mc/GBM, 2);
    gemm_mfma<<<ggrid, dim3(256), 0, stream>>>(X,  XP,   XP,  (const u16*)0, 0,  wb0, XP,  b0, Ha);
    gemm_mfma<<<ggrid, dim3(256), 0, stream>>>(Ha, MLPW, 256, (const u16*)0, 0,  wb1, 256, b1, Hb);
    gemm_mfma<<<ggrid, dim3(256), 0, stream>>>(Hb, MLPW, 256, (const u16*)0, 0,  wb2, 256, b2, Ha);
    gemm_mfma<<<ggrid, dim3(256), 0, stream>>>(Ha, MLPW, 256, X, XP,            wb3, K3P, b3, Hb);
    out_kernel<<<dim3(mc/4), dim3(256), 0, stream>>>(Hb, wo, bo, out, (int)m0, mc);
  }
}

// Round 13
// 684.399 us; speedup vs baseline: 1.2798x; 1.2798x over previous
//
#include <hip/hip_runtime.h>
#include <math.h>

#define BFULL 8
#define HH 64
#define WWI 64
#define CC 256
#define NN 16384
#define INDIM 810
#define XP 832          // X padded cols (zero-filled 810..831)
#define K3P 1088        // concat layer K padded (256 + 832)
#define MLPW 256
#define FBM 128         // fused-MLP rows per block
#define HSTR 264        // H LDS row stride (u16): 256+8 pad -> 2-way bank conflicts (free)
#define ASTR 40         // X-chunk LDS row stride (u16): 32+8 pad

typedef unsigned short u16;
typedef __attribute__((ext_vector_type(8))) short short8;
typedef __attribute__((ext_vector_type(4))) float f32x4;

__device__ __forceinline__ u16 f2bf(float f){
  union{float f; unsigned u;} v; v.f=f;
  unsigned r = v.u + 0x7FFFu + ((v.u>>16)&1u);   // RNE
  return (u16)(r>>16);
}
__device__ __forceinline__ float bf2f(u16 h){
  union{unsigned u; float f;} v; v.u = ((unsigned)h)<<16; return v.f;
}
// tanh-approx gelu; 1-2/(e^{2z}+1) saturates cleanly (no NaN at inf/0)
__device__ __forceinline__ float gelu_fast(float x){
  float z = 0.7978845608028654f*(x + 0.044715f*x*x*x);
  float e = __expf(2.0f*z);
  float t = 1.0f - 2.0f/(e + 1.0f);
  return 0.5f*x*(1.0f+t);
}

// ---------------- pyramid resize (jax.image.resize bilinear, antialias=True) ----------------
template<int OUTD, int RR>
__global__ __launch_bounds__(256) void resize_kernel(const float* __restrict__ in,
                                                     float* __restrict__ out){
  int bidx = blockIdx.x;
  int ox = bidx % OUTD;
  int oy = (bidx / OUTD) % OUTD;
  int b  = bidx / (OUTD*OUTD);
  int c = threadIdx.x;

  float sy = (oy + 0.5f)*RR - 0.5f;
  float sx = (ox + 0.5f)*RR - 0.5f;
  int jy0 = (int)floorf(sy) - RR + 1;
  int jx0 = (int)floorf(sx) - RR + 1;

  float wy[2*RR], wx[2*RR];
  int   jys[2*RR], jxs[2*RR];
  int cy=0, cx=0; float sumy=0.f, sumx=0.f;
  #pragma unroll
  for(int t=0;t<2*RR;t++){
    int j = jy0 + t;
    if(j>=0 && j<HH){
      float w = 1.0f - fabsf((float)j - sy)/(float)RR;
      if(w > 0.f){ jys[cy]=j; wy[cy]=w; sumy+=w; cy++; }
    }
  }
  #pragma unroll
  for(int t=0;t<2*RR;t++){
    int j = jx0 + t;
    if(j>=0 && j<WWI){
      float w = 1.0f - fabsf((float)j - sx)/(float)RR;
      if(w > 0.f){ jxs[cx]=j; wx[cx]=w; sumx+=w; cx++; }
    }
  }
  float acc = 0.f;
  for(int i=0;i<cy;i++)
    for(int j=0;j<cx;j++)
      acc += wy[i]*wx[j]*in[(((size_t)b*HH + jys[i])*WWI + jxs[j])*CC + c];
  acc /= (sumy*sumx);
  out[(((size_t)b*OUTD + oy)*OUTD + ox)*CC + c] = acc;
}

// ------------- posenc + pyramid sampling -> X rows [chunk][XP] bf16, vectorized -------------
// 256 threads = 2 rows x 128 lanes. Per row: lanes 0..63 handle 4 channels (float4),
// lanes 64..105 posenc, lanes 106..127 zero the pad.
__global__ __launch_bounds__(256) void sample_encode_v2(
    const float* __restrict__ fg, const float* __restrict__ pyr1,
    const float* __restrict__ pyr2, const float* __restrict__ coords,
    u16* __restrict__ X, int m0, int mcount){
  int mi = blockIdx.x*2 + (threadIdx.x >> 7);
  if(mi >= mcount) return;
  int u = threadIdx.x & 127;
  int m = m0 + mi;
  int b = m / NN;
  int n = m % NN;
  float c0 = coords[(size_t)n*2 + 0];
  float c1 = coords[(size_t)n*2 + 1];
  u16* xrow = X + (size_t)mi*XP;

  if(u >= 64){
    if(u < 106){
      int p = u - 64;
      float v;
      if(p < 2){ v = (p==0) ? c0 : c1; }
      else {
        int k = (p-2) >> 2;
        int r = (p-2) & 3;
        float f = (float)(1u<<k) * 3.14159265358979323846f;
        float a = (r & 1) ? c1 : c0;
        v = (r < 2) ? sinf(a*f) : cosf(a*f);
      }
      xrow[p] = f2bf(v);
    } else {
      xrow[INDIM + (u - 106)] = 0;       // pad 810..831 (22 cols)
    }
    return;
  }

  int c4 = u*4;
  const float* grids[3];
  grids[0] = fg   + (size_t)b*HH*WWI*CC;
  grids[1] = pyr1 + (size_t)b*32*32*CC;
  grids[2] = pyr2 + (size_t)b*16*16*CC;
  const int dims[3] = {64, 32, 16};

  #pragma unroll
  for(int lvl=0; lvl<3; lvl++){
    int d = dims[lvl];
    float yy = (c0 + 1.0f)*0.5f*(float)(d-1);
    float xx = (c1 + 1.0f)*0.5f*(float)(d-1);
    yy = fminf(fmaxf(yy, 0.0f), (float)(d-1));
    xx = fminf(fmaxf(xx, 0.0f), (float)(d-1));
    int y0 = (int)yy, x0 = (int)xx;
    int y1 = min(y0+1, d-1), x1 = min(x0+1, d-1);
    float ty = yy - (float)y0, tx = xx - (float)x0;
    const float* g = grids[lvl];
    float4 v00 = *(const float4*)&g[((size_t)y0*d + x0)*CC + c4];
    float4 v01 = *(const float4*)&g[((size_t)y0*d + x1)*CC + c4];
    float4 v10 = *(const float4*)&g[((size_t)y1*d + x0)*CC + c4];
    float4 v11 = *(const float4*)&g[((size_t)y1*d + x1)*CC + c4];
    float w00 = (1.f-ty)*(1.f-tx), w01 = (1.f-ty)*tx, w10 = ty*(1.f-tx), w11 = ty*tx;
    float r0 = w00*v00.x + w01*v01.x + w10*v10.x + w11*v11.x;
    float r1 = w00*v00.y + w01*v01.y + w10*v10.y + w11*v11.y;
    float r2 = w00*v00.z + w01*v01.z + w10*v10.z + w11*v11.z;
    float r3 = w00*v00.w + w01*v01.w + w10*v10.w + w11*v11.w;
    unsigned lo = (unsigned)f2bf(r0) | ((unsigned)f2bf(r1) << 16);
    unsigned hi = (unsigned)f2bf(r2) | ((unsigned)f2bf(r3) << 16);
    unsigned* dst = (unsigned*)&xrow[42 + lvl*CC + c4];   // byte off 84+8u+512lvl: 4B-aligned
    dst[0] = lo; dst[1] = hi;
  }
}

// ---------------- weight convert: W[k][256] fp32 -> Wb[n][Kp] bf16 (B^T, zero-padded) ------
__global__ __launch_bounds__(256) void wconv(const float* __restrict__ W,
                                             u16* __restrict__ Wb, int K, int Kp){
  int idx = blockIdx.x*256 + threadIdx.x;
  if(idx >= 256*Kp) return;
  int n = idx / Kp, k = idx % Kp;
  float v = (k < K) ? W[(size_t)k*MLPW + n] : 0.f;
  Wb[idx] = f2bf(v);
}

// ---------------- fused MLP: all 4 layers + 256->3 output, H resident in LDS ----------------
// 512 threads (8 waves), block owns 128 rows. Wave (wv) tile: 64x64 at
// wr=(wv>>2)*64, wc=(wv&3)*64. Weights read as B-fragments straight from L2.
__global__ __launch_bounds__(512, 4) void fused_mlp(
    const u16* __restrict__ X,
    const u16* __restrict__ wb0, const u16* __restrict__ wb1,
    const u16* __restrict__ wb2, const u16* __restrict__ wb3,
    const float* __restrict__ b0, const float* __restrict__ b1,
    const float* __restrict__ b2, const float* __restrict__ b3,
    const float* __restrict__ wo, const float* __restrict__ bo,
    float* __restrict__ out, int m0){
  __shared__ u16 Hs[FBM*HSTR];     // 67584 B
  __shared__ u16 As[FBM*ASTR];     // 10240 B  (77824 total -> 2 blocks/CU)

  int tid  = threadIdx.x;
  int lane = tid & 63, wv = tid >> 6;
  int wr = (wv>>2)*64, wc = (wv&3)*64;
  int rl = lane & 15, cl = lane & 15;
  int koffe = (lane >> 4)*8;          // k-slice offset within a 32-K fragment (u16 elems)
  int rg = (lane >> 4)*4;             // C/D row group

  size_t gm = (size_t)blockIdx.x*FBM; // row base within chunk

  f32x4 acc[4][4];
  #pragma unroll
  for(int i=0;i<4;i++)
    #pragma unroll
    for(int j=0;j<4;j++) acc[i][j] = (f32x4){0.f,0.f,0.f,0.f};

  // stage one 128x32 X chunk (xk = starting col) into As via reg->LDS
  int srow = tid >> 2, skp = tid & 3;
  auto stageX = [&](int xk){
    uint4 v = *(const uint4*)&X[(gm + srow)*XP + xk + skp*8];
    *(uint4*)&As[srow*ASTR + skp*8] = v;
  };
  // one 32-K MFMA step: A from LDS (base aLDS, row stride astride, col ak), B from global
  auto mfma_chunk = [&](const u16* __restrict__ bw, int KpW, int gk,
                        const u16* __restrict__ aLDS, int astride, int ak){
    short8 af[4], bfr[4];
    #pragma unroll
    for(int f=0; f<4; f++)
      af[f] = *(const short8*)&aLDS[(wr + f*16 + rl)*astride + ak + koffe];
    #pragma unroll
    for(int f=0; f<4; f++)
      bfr[f] = *(const short8*)&bw[(size_t)(wc + f*16 + rl)*KpW + gk + koffe];
    #pragma unroll
    for(int i=0;i<4;i++)
      #pragma unroll
      for(int j=0;j<4;j++)
        acc[i][j] = __builtin_amdgcn_mfma_f32_16x16x32_bf16(af[i], bfr[j], acc[i][j], 0,0,0);
  };
  // gelu + bf16 + write into Hs (in place), then clear acc
  auto epilogue = [&](const float* __restrict__ bias){
    __syncthreads();                       // all reads of Hs finished
    #pragma unroll
    for(int j=0;j<4;j++){
      int ncol = wc + j*16 + cl;
      float bv = bias[ncol];
      #pragma unroll
      for(int i=0;i<4;i++)
        #pragma unroll
        for(int r=0;r<4;r++){
          int row = wr + i*16 + rg + r;
          Hs[row*HSTR + ncol] = f2bf(gelu_fast(acc[i][j][r] + bv));
        }
    }
    __syncthreads();
    #pragma unroll
    for(int i=0;i<4;i++)
      #pragma unroll
      for(int j=0;j<4;j++) acc[i][j] = (f32x4){0.f,0.f,0.f,0.f};
  };

  // ---- layer 0: X(832) @ w0 ----
  for(int kc=0; kc<XP/32; kc++){
    stageX(kc*32);
    __syncthreads();
    mfma_chunk(wb0, XP, kc*32, As, ASTR, 0);
    __syncthreads();
  }
  epilogue(b0);
  // ---- layer 1,2: H(256) @ w ----
  #pragma unroll 1
  for(int kc=0; kc<8; kc++) mfma_chunk(wb1, 256, kc*32, Hs, HSTR, kc*32);
  epilogue(b1);
  #pragma unroll 1
  for(int kc=0; kc<8; kc++) mfma_chunk(wb2, 256, kc*32, Hs, HSTR, kc*32);
  epilogue(b2);
  // ---- layer 3: concat(H,X)(1088) @ w3 ----
  #pragma unroll 1
  for(int kc=0; kc<8; kc++) mfma_chunk(wb3, K3P, kc*32, Hs, HSTR, kc*32);
  for(int kc=8; kc<K3P/32; kc++){
    __syncthreads();                       // As safe to overwrite (prev chunk consumed)
    stageX((kc-8)*32);
    __syncthreads();
    mfma_chunk(wb3, K3P, kc*32, As, ASTR, 0);
  }
  epilogue(b3);

  // ---- output layer: tanh(H3 @ wo + bo), from LDS ----
  int orow = wv*16 + (lane >> 2);
  int kb = (lane & 3)*64;
  float p0=0.f, p1=0.f, p2=0.f;
  for(int i=0;i<64;i++){
    float hv = bf2f(Hs[orow*HSTR + kb + i]);
    const float* w = &wo[(size_t)(kb+i)*3];
    p0 += hv*w[0]; p1 += hv*w[1]; p2 += hv*w[2];
  }
  p0 += __shfl_xor(p0,1); p0 += __shfl_xor(p0,2);
  p1 += __shfl_xor(p1,1); p1 += __shfl_xor(p1,2);
  p2 += __shfl_xor(p2,1); p2 += __shfl_xor(p2,2);
  if((lane & 3) == 0){
    size_t gr = (size_t)m0 + gm + orow;
    out[gr*3+0] = tanhf(p0 + bo[0]);
    out[gr*3+1] = tanhf(p1 + bo[1]);
    out[gr*3+2] = tanhf(p2 + bo[2]);
  }
}

extern "C" void kernel_launch(void* const* d_in, const int* in_sizes, int n_in,
                              void* d_out, int out_size, void* d_ws, size_t ws_size,
                              hipStream_t stream){
  const float* fg     = (const float*)d_in[0];
  const float* coords = (const float*)d_in[1];
  const float* w0 = (const float*)d_in[2];  const float* b0 = (const float*)d_in[3];
  const float* w1 = (const float*)d_in[4];  const float* b1 = (const float*)d_in[5];
  const float* w2 = (const float*)d_in[6];  const float* b2 = (const float*)d_in[7];
  const float* w3 = (const float*)d_in[8];  const float* b3 = (const float*)d_in[9];
  const float* wo = (const float*)d_in[10]; const float* bo = (const float*)d_in[11];
  float* out = (float*)d_out;

  char* ws = (char*)d_ws;
  size_t off = 0;
  auto alloc = [&](size_t bytes)->void*{
    void* p = ws + off;
    off += (bytes + 255) & ~(size_t)255;
    return p;
  };
  auto rnd = [](size_t bytes)->size_t{ return (bytes + 255) & ~(size_t)255; };

  size_t fixed =
      rnd((size_t)BFULL*32*32*CC*4) + rnd((size_t)BFULL*16*16*CC*4) +
      rnd((size_t)256*XP*2) + rnd((size_t)256*256*2) +
      rnd((size_t)256*256*2) + rnd((size_t)256*K3P*2);

  const size_t Mtot = (size_t)BFULL*NN; // 131072
  size_t chunk = Mtot;
  while(chunk > 128){
    size_t need = fixed + rnd(chunk*(size_t)XP*2);
    if(need <= ws_size) break;
    chunk >>= 1;
  }
  size_t min_need = fixed + rnd(chunk*(size_t)XP*2);
  if(min_need > ws_size || (chunk % 128) != 0) return;

  float* pyr1 = (float*)alloc((size_t)BFULL*32*32*CC*4);
  float* pyr2 = (float*)alloc((size_t)BFULL*16*16*CC*4);
  u16* wb0 = (u16*)alloc((size_t)256*XP*2);
  u16* wb1 = (u16*)alloc((size_t)256*256*2);
  u16* wb2 = (u16*)alloc((size_t)256*256*2);
  u16* wb3 = (u16*)alloc((size_t)256*K3P*2);
  u16* X  = (u16*)alloc(chunk*(size_t)XP*2);

  resize_kernel<32,2><<<dim3(BFULL*32*32), dim3(256), 0, stream>>>(fg, pyr1);
  resize_kernel<16,4><<<dim3(BFULL*16*16), dim3(256), 0, stream>>>(fg, pyr2);
  wconv<<<dim3((256*XP +255)/256), dim3(256), 0, stream>>>(w0, wb0, INDIM, XP);
  wconv<<<dim3((256*256 +255)/256), dim3(256), 0, stream>>>(w1, wb1, 256, 256);
  wconv<<<dim3((256*256 +255)/256), dim3(256), 0, stream>>>(w2, wb2, 256, 256);
  wconv<<<dim3((256*K3P +255)/256), dim3(256), 0, stream>>>(w3, wb3, MLPW+INDIM, K3P);

  for(size_t m0=0; m0<Mtot; m0+=chunk){
    int mc = (int)chunk;
    sample_encode_v2<<<dim3(mc/2), dim3(256), 0, stream>>>(fg, pyr1, pyr2, coords, X, (int)m0, mc);
    fused_mlp<<<dim3(mc/FBM), dim3(512), 0, stream>>>(X, wb0, wb1, wb2, wb3,
                                                      b0, b1, b2, b3, wo, bo,
                                                      out, (int)m0);
  }
}

// Round 14
// 665.697 us; speedup vs baseline: 1.3158x; 1.0281x over previous
//
#include <hip/hip_runtime.h>
#include <math.h>

#define BFULL 8
#define HH 64
#define WWI 64
#define CC 256
#define NN 16384
#define INDIM 810
#define XP 832          // X padded cols (zero-filled 810..831)
#define K3P 1088        // concat layer K padded (256 + 832)
#define MLPW 256
#define FBM 128         // fused-MLP rows per block
#define HSTR 260        // H LDS row stride (u16): 130 dwords -> uniform banks (reads 8/bank min, epi writes 2-way free)
#define ASTR 40         // X-chunk LDS row stride (u16)

typedef unsigned short u16;
typedef __attribute__((ext_vector_type(8))) short short8;
typedef __attribute__((ext_vector_type(4))) float f32x4;

__device__ __forceinline__ u16 f2bf(float f){
  union{float f; unsigned u;} v; v.f=f;
  unsigned r = v.u + 0x7FFFu + ((v.u>>16)&1u);   // RNE
  return (u16)(r>>16);
}
__device__ __forceinline__ float bf2f(u16 h){
  union{unsigned u; float f;} v; v.u = ((unsigned)h)<<16; return v.f;
}
// tanh-approx gelu; 1-2/(e^{2z}+1) saturates cleanly (no NaN at inf/0)
__device__ __forceinline__ float gelu_fast(float x){
  float z = 0.7978845608028654f*(x + 0.044715f*x*x*x);
  float e = __expf(2.0f*z);
  float t = 1.0f - 2.0f/(e + 1.0f);
  return 0.5f*x*(1.0f+t);
}

// ---------------- pyramid resize (jax.image.resize bilinear, antialias=True) ----------------
template<int OUTD, int RR>
__global__ __launch_bounds__(256) void resize_kernel(const float* __restrict__ in,
                                                     float* __restrict__ out){
  int bidx = blockIdx.x;
  int ox = bidx % OUTD;
  int oy = (bidx / OUTD) % OUTD;
  int b  = bidx / (OUTD*OUTD);
  int c = threadIdx.x;

  float sy = (oy + 0.5f)*RR - 0.5f;
  float sx = (ox + 0.5f)*RR - 0.5f;
  int jy0 = (int)floorf(sy) - RR + 1;
  int jx0 = (int)floorf(sx) - RR + 1;

  float wy[2*RR], wx[2*RR];
  int   jys[2*RR], jxs[2*RR];
  int cy=0, cx=0; float sumy=0.f, sumx=0.f;
  #pragma unroll
  for(int t=0;t<2*RR;t++){
    int j = jy0 + t;
    if(j>=0 && j<HH){
      float w = 1.0f - fabsf((float)j - sy)/(float)RR;
      if(w > 0.f){ jys[cy]=j; wy[cy]=w; sumy+=w; cy++; }
    }
  }
  #pragma unroll
  for(int t=0;t<2*RR;t++){
    int j = jx0 + t;
    if(j>=0 && j<WWI){
      float w = 1.0f - fabsf((float)j - sx)/(float)RR;
      if(w > 0.f){ jxs[cx]=j; wx[cx]=w; sumx+=w; cx++; }
    }
  }
  float acc = 0.f;
  for(int i=0;i<cy;i++)
    for(int j=0;j<cx;j++)
      acc += wy[i]*wx[j]*in[(((size_t)b*HH + jys[i])*WWI + jxs[j])*CC + c];
  acc /= (sumy*sumx);
  out[(((size_t)b*OUTD + oy)*OUTD + ox)*CC + c] = acc;
}

// ------------- posenc + pyramid sampling -> X rows [chunk][XP] bf16, vectorized -------------
__global__ __launch_bounds__(256) void sample_encode_v2(
    const float* __restrict__ fg, const float* __restrict__ pyr1,
    const float* __restrict__ pyr2, const float* __restrict__ coords,
    u16* __restrict__ X, int m0, int mcount){
  int mi = blockIdx.x*2 + (threadIdx.x >> 7);
  if(mi >= mcount) return;
  int u = threadIdx.x & 127;
  int m = m0 + mi;
  int b = m / NN;
  int n = m % NN;
  float c0 = coords[(size_t)n*2 + 0];
  float c1 = coords[(size_t)n*2 + 1];
  u16* xrow = X + (size_t)mi*XP;

  if(u >= 64){
    if(u < 106){
      int p = u - 64;
      float v;
      if(p < 2){ v = (p==0) ? c0 : c1; }
      else {
        int k = (p-2) >> 2;
        int r = (p-2) & 3;
        float f = (float)(1u<<k) * 3.14159265358979323846f;
        float a = (r & 1) ? c1 : c0;
        v = (r < 2) ? sinf(a*f) : cosf(a*f);
      }
      xrow[p] = f2bf(v);
    } else {
      xrow[INDIM + (u - 106)] = 0;       // pad 810..831 (22 cols)
    }
    return;
  }

  int c4 = u*4;
  const float* grids[3];
  grids[0] = fg   + (size_t)b*HH*WWI*CC;
  grids[1] = pyr1 + (size_t)b*32*32*CC;
  grids[2] = pyr2 + (size_t)b*16*16*CC;
  const int dims[3] = {64, 32, 16};

  #pragma unroll
  for(int lvl=0; lvl<3; lvl++){
    int d = dims[lvl];
    float yy = (c0 + 1.0f)*0.5f*(float)(d-1);
    float xx = (c1 + 1.0f)*0.5f*(float)(d-1);
    yy = fminf(fmaxf(yy, 0.0f), (float)(d-1));
    xx = fminf(fmaxf(xx, 0.0f), (float)(d-1));
    int y0 = (int)yy, x0 = (int)xx;
    int y1 = min(y0+1, d-1), x1 = min(x0+1, d-1);
    float ty = yy - (float)y0, tx = xx - (float)x0;
    const float* g = grids[lvl];
    float4 v00 = *(const float4*)&g[((size_t)y0*d + x0)*CC + c4];
    float4 v01 = *(const float4*)&g[((size_t)y0*d + x1)*CC + c4];
    float4 v10 = *(const float4*)&g[((size_t)y1*d + x0)*CC + c4];
    float4 v11 = *(const float4*)&g[((size_t)y1*d + x1)*CC + c4];
    float w00 = (1.f-ty)*(1.f-tx), w01 = (1.f-ty)*tx, w10 = ty*(1.f-tx), w11 = ty*tx;
    float r0 = w00*v00.x + w01*v01.x + w10*v10.x + w11*v11.x;
    float r1 = w00*v00.y + w01*v01.y + w10*v10.y + w11*v11.y;
    float r2 = w00*v00.z + w01*v01.z + w10*v10.z + w11*v11.z;
    float r3 = w00*v00.w + w01*v01.w + w10*v10.w + w11*v11.w;
    unsigned lo = (unsigned)f2bf(r0) | ((unsigned)f2bf(r1) << 16);
    unsigned hi = (unsigned)f2bf(r2) | ((unsigned)f2bf(r3) << 16);
    unsigned* dst = (unsigned*)&xrow[42 + lvl*CC + c4];
    dst[0] = lo; dst[1] = hi;
  }
}

// ---------------- weight convert: W[k][256] fp32 -> Wb[n][Kp] bf16 (B^T, zero-padded) ------
__global__ __launch_bounds__(256) void wconv(const float* __restrict__ W,
                                             u16* __restrict__ Wb, int K, int Kp){
  int idx = blockIdx.x*256 + threadIdx.x;
  if(idx >= 256*Kp) return;
  int n = idx / Kp, k = idx % Kp;
  float v = (k < K) ? W[(size_t)k*MLPW + n] : 0.f;
  Wb[idx] = f2bf(v);
}

// wo [256][3] fp32 -> wob[16][256] bf16 (B^T, rows 3..15 zero)
__global__ __launch_bounds__(256) void wconv_out(const float* __restrict__ wo,
                                                 u16* __restrict__ wob){
  int idx = blockIdx.x*256 + threadIdx.x;
  if(idx >= 16*256) return;
  int n = idx >> 8, k = idx & 255;
  float v = (n < 3) ? wo[(size_t)k*3 + n] : 0.f;
  wob[idx] = f2bf(v);
}

// ---------------- fused MLP: all 4 layers + MFMA output, H resident in LDS ----------------
__global__ __launch_bounds__(512, 4) void fused_mlp(
    const u16* __restrict__ X,
    const u16* __restrict__ wb0, const u16* __restrict__ wb1,
    const u16* __restrict__ wb2, const u16* __restrict__ wb3,
    const u16* __restrict__ wob,
    const float* __restrict__ b0, const float* __restrict__ b1,
    const float* __restrict__ b2, const float* __restrict__ b3,
    const float* __restrict__ bo,
    float* __restrict__ out, int m0){
  __shared__ u16 Hs[FBM*HSTR];     // 66560 B
  __shared__ u16 As[FBM*ASTR];     // 10240 B  (76800 total -> 2 blocks/CU)

  int tid  = threadIdx.x;
  int lane = tid & 63, wv = tid >> 6;
  int wr = (wv>>2)*64, wc = (wv&3)*64;
  int rl = lane & 15;
  int koffe = (lane >> 4)*8;          // k-slice offset within a 32-K fragment
  int rg = (lane >> 4)*4;             // C/D row group

  size_t gm = (size_t)blockIdx.x*FBM;

  f32x4 acc[4][4];
  #pragma unroll
  for(int i=0;i<4;i++)
    #pragma unroll
    for(int j=0;j<4;j++) acc[i][j] = (f32x4){0.f,0.f,0.f,0.f};

  int srow = tid >> 2, skp = tid & 3;
  const u16* xbase = X + (gm + srow)*XP + skp*8;

  auto loadA = [&](const u16* aL, int astr, int ak, short8 af[4]){
    #pragma unroll
    for(int f=0; f<4; f++)
      af[f] = *(const short8*)&aL[(wr + f*16 + rl)*astr + ak + koffe];
  };
  auto loadB = [&](const u16* bw, int Kp2, int gk, short8 bf[4]){
    #pragma unroll
    for(int f=0; f<4; f++)
      bf[f] = *(const short8*)&bw[(size_t)(wc + f*16 + rl)*Kp2 + gk + koffe];
  };
  auto domfma = [&](short8 af[4], short8 bf[4]){
    #pragma unroll
    for(int i=0;i<4;i++)
      #pragma unroll
      for(int j=0;j<4;j++)
        acc[i][j] = __builtin_amdgcn_mfma_f32_16x16x32_bf16(af[i], bf[j], acc[i][j], 0,0,0);
  };
  auto epilogue = [&](const float* __restrict__ bias){
    __syncthreads();                       // all reads of Hs finished
    #pragma unroll
    for(int j=0;j<4;j++){
      int ncol = wc + j*16 + rl;
      float bv = bias[ncol];
      #pragma unroll
      for(int i=0;i<4;i++)
        #pragma unroll
        for(int r=0;r<4;r++){
          int row = wr + i*16 + rg + r;
          Hs[row*HSTR + ncol] = f2bf(gelu_fast(acc[i][j][r] + bv));
        }
    }
    __syncthreads();
    #pragma unroll
    for(int i=0;i<4;i++)
      #pragma unroll
      for(int j=0;j<4;j++) acc[i][j] = (f32x4){0.f,0.f,0.f,0.f};
  };
  // X-staged MFMA loop (layers 0 and 3's X part): reg-prefetch next chunk
  auto xloop = [&](const u16* bw, int Kp2, int gbase){
    uint4 xv = *(const uint4*)(xbase);
    *(uint4*)&As[srow*ASTR + skp*8] = xv;
    __syncthreads();
    for(int kc=0; kc<26; kc++){
      uint4 xn;
      if(kc < 25) xn = *(const uint4*)(xbase + (kc+1)*32);   // issue early (HBM hidden)
      short8 bf[4]; loadB(bw, Kp2, gbase + kc*32, bf);
      short8 af[4]; loadA(As, ASTR, 0, af);
      domfma(af, bf);
      __syncthreads();                  // As reads done
      if(kc < 25) *(uint4*)&As[srow*ASTR + skp*8] = xn;
      __syncthreads();                  // As ready
    }
  };
  // H-resident layer (8 chunks, fully unrolled -> compiler pipelines weight loads)
  auto hloop = [&](const u16* bw, int Kp2, int gbase){
    #pragma unroll
    for(int kc=0; kc<8; kc++){
      short8 bf[4]; loadB(bw, Kp2, gbase + kc*32, bf);
      short8 af[4]; loadA(Hs, HSTR, kc*32, af);
      domfma(af, bf);
    }
  };

  // ---- layer 0: X(832) @ w0 ----
  xloop(wb0, XP, 0);
  epilogue(b0);
  // ---- layers 1,2: H(256) @ w ----
  hloop(wb1, 256, 0);
  epilogue(b1);
  hloop(wb2, 256, 0);
  epilogue(b2);
  // ---- layer 3: concat(H,X)(1088) @ w3 ----
  hloop(wb3, K3P, 0);
  xloop(wb3, K3P, 256);
  epilogue(b3);

  // ---- output layer via MFMA: tanh(H3 @ wob^T + bo); waves 0,1 cover 128 rows ----
  if(wv < 2){
    f32x4 oa[4];
    #pragma unroll
    for(int i=0;i<4;i++) oa[i] = (f32x4){0.f,0.f,0.f,0.f};
    #pragma unroll
    for(int c=0;c<8;c++){
      short8 af[4];
      #pragma unroll
      for(int f=0; f<4; f++)
        af[f] = *(const short8*)&Hs[(wv*64 + f*16 + rl)*HSTR + c*32 + koffe];
      short8 bf1 = *(const short8*)&wob[(size_t)rl*256 + c*32 + koffe];
      #pragma unroll
      for(int i=0;i<4;i++)
        oa[i] = __builtin_amdgcn_mfma_f32_16x16x32_bf16(af[i], bf1, oa[i], 0,0,0);
    }
    if(rl < 3){
      float bv = bo[rl];
      #pragma unroll
      for(int i=0;i<4;i++)
        #pragma unroll
        for(int r=0;r<4;r++){
          size_t gr = (size_t)m0 + gm + wv*64 + i*16 + rg + r;
          out[gr*3 + rl] = tanhf(oa[i][r] + bv);
        }
    }
  }
}

extern "C" void kernel_launch(void* const* d_in, const int* in_sizes, int n_in,
                              void* d_out, int out_size, void* d_ws, size_t ws_size,
                              hipStream_t stream){
  const float* fg     = (const float*)d_in[0];
  const float* coords = (const float*)d_in[1];
  const float* w0 = (const float*)d_in[2];  const float* b0 = (const float*)d_in[3];
  const float* w1 = (const float*)d_in[4];  const float* b1 = (const float*)d_in[5];
  const float* w2 = (const float*)d_in[6];  const float* b2 = (const float*)d_in[7];
  const float* w3 = (const float*)d_in[8];  const float* b3 = (const float*)d_in[9];
  const float* wo = (const float*)d_in[10]; const float* bo = (const float*)d_in[11];
  float* out = (float*)d_out;

  char* ws = (char*)d_ws;
  size_t off = 0;
  auto alloc = [&](size_t bytes)->void*{
    void* p = ws + off;
    off += (bytes + 255) & ~(size_t)255;
    return p;
  };
  auto rnd = [](size_t bytes)->size_t{ return (bytes + 255) & ~(size_t)255; };

  size_t fixed =
      rnd((size_t)BFULL*32*32*CC*4) + rnd((size_t)BFULL*16*16*CC*4) +
      rnd((size_t)256*XP*2) + rnd((size_t)256*256*2) +
      rnd((size_t)256*256*2) + rnd((size_t)256*K3P*2) + rnd((size_t)16*256*2);

  const size_t Mtot = (size_t)BFULL*NN; // 131072
  size_t chunk = Mtot;
  while(chunk > 128){
    size_t need = fixed + rnd(chunk*(size_t)XP*2);
    if(need <= ws_size) break;
    chunk >>= 1;
  }
  size_t min_need = fixed + rnd(chunk*(size_t)XP*2);
  if(min_need > ws_size || (chunk % 128) != 0) return;

  float* pyr1 = (float*)alloc((size_t)BFULL*32*32*CC*4);
  float* pyr2 = (float*)alloc((size_t)BFULL*16*16*CC*4);
  u16* wb0 = (u16*)alloc((size_t)256*XP*2);
  u16* wb1 = (u16*)alloc((size_t)256*256*2);
  u16* wb2 = (u16*)alloc((size_t)256*256*2);
  u16* wb3 = (u16*)alloc((size_t)256*K3P*2);
  u16* wob = (u16*)alloc((size_t)16*256*2);
  u16* X  = (u16*)alloc(chunk*(size_t)XP*2);

  resize_kernel<32,2><<<dim3(BFULL*32*32), dim3(256), 0, stream>>>(fg, pyr1);
  resize_kernel<16,4><<<dim3(BFULL*16*16), dim3(256), 0, stream>>>(fg, pyr2);
  wconv<<<dim3((256*XP +255)/256), dim3(256), 0, stream>>>(w0, wb0, INDIM, XP);
  wconv<<<dim3((256*256 +255)/256), dim3(256), 0, stream>>>(w1, wb1, 256, 256);
  wconv<<<dim3((256*256 +255)/256), dim3(256), 0, stream>>>(w2, wb2, 256, 256);
  wconv<<<dim3((256*K3P +255)/256), dim3(256), 0, stream>>>(w3, wb3, MLPW+INDIM, K3P);
  wconv_out<<<dim3(16), dim3(256), 0, stream>>>(wo, wob);

  for(size_t m0=0; m0<Mtot; m0+=chunk){
    int mc = (int)chunk;
    sample_encode_v2<<<dim3(mc/2), dim3(256), 0, stream>>>(fg, pyr1, pyr2, coords, X, (int)m0, mc);
    fused_mlp<<<dim3(mc/FBM), dim3(512), 0, stream>>>(X, wb0, wb1, wb2, wb3, wob,
                                                      b0, b1, b2, b3, bo,
                                                      out, (int)m0);
  }
}